// Round 2
// baseline (281.236 us; speedup 1.0000x reference)
//
#include <hip/hip_runtime.h>
#include <hip/hip_bf16.h>
#include <stdint.h>

#define DIM    1024
#define SEQ    2048
#define NB     2
#define NH     16
#define HD     64
#define NROWS  (NB*SEQ)   // 4096

typedef unsigned short u16;
typedef __attribute__((ext_vector_type(8))) short bf16x8;
typedef __attribute__((ext_vector_type(4))) float f32x4;
typedef __attribute__((ext_vector_type(4))) unsigned short u16x4;

#define NEG_INF (-__builtin_inff())

// float -> bf16 with round-to-nearest-even
__device__ __forceinline__ u16 f2bf(float f) {
    union { float f; uint32_t u; } x; x.f = f;
    uint32_t r = x.u + 0x7FFFu + ((x.u >> 16) & 1u);
    return (u16)(r >> 16);
}

// async global->LDS, 16B per lane. LDS dest is wave-uniform base + lane*16.
__device__ __forceinline__ void gload_lds16(const void* g, void* l) {
    __builtin_amdgcn_global_load_lds(
        (const __attribute__((address_space(1))) void*)g,
        (__attribute__((address_space(3))) void*)l, 16, 0, 0);
}

// ---------------------------------------------------------------------------
// x (fp32 [4096][1024]) -> bf16. 4 elems/thread, exact cover.
// ---------------------------------------------------------------------------
__global__ __launch_bounds__(256)
void cvt_x(const float* __restrict__ in, u16* __restrict__ out)
{
    size_t i = (size_t)blockIdx.x * 256 + threadIdx.x;   // < 1048576
    float4 f = *(const float4*)&in[i * 4];
    u16x4 o = { f2bf(f.x), f2bf(f.y), f2bf(f.z), f2bf(f.w) };
    *(u16x4*)&out[i * 4] = o;
}

// ---------------------------------------------------------------------------
// W (fp32 [K=1024][N=1024]) -> Wt (bf16 [N][K]) — LDS-tiled 64x64 transpose.
// z selects which of the 4 weight matrices.
// ---------------------------------------------------------------------------
__global__ __launch_bounds__(256)
void cvt_w(const float* __restrict__ Wq, const float* __restrict__ Wk,
           const float* __restrict__ Wv, const float* __restrict__ Wo,
           u16* __restrict__ Wqt, u16* __restrict__ Wkt,
           u16* __restrict__ Wvt, u16* __restrict__ Wot)
{
    __shared__ u16 Ws[64][68];
    const int z = blockIdx.z;
    const float* W = z == 0 ? Wq : z == 1 ? Wk : z == 2 ? Wv : Wo;
    u16* Wt        = z == 0 ? Wqt : z == 1 ? Wkt : z == 2 ? Wvt : Wot;
    const int k0 = blockIdx.x * 64;
    const int n0 = blockIdx.y * 64;
    const int tid = threadIdx.x;

    #pragma unroll
    for (int it = 0; it < 4; ++it) {
        int idx = tid + it * 256;
        int r = idx >> 4, cq = idx & 15;
        float4 f = *(const float4*)&W[(size_t)(k0 + r) * DIM + n0 + cq * 4];
        u16x4 o = { f2bf(f.x), f2bf(f.y), f2bf(f.z), f2bf(f.w) };
        *(u16x4*)&Ws[r][cq * 4] = o;
    }
    __syncthreads();
    #pragma unroll
    for (int it = 0; it < 4; ++it) {
        int idx = tid + it * 256;
        int rr = idx >> 4, cq = idx & 15;
        u16x4 o = { Ws[cq*4+0][rr], Ws[cq*4+1][rr], Ws[cq*4+2][rr], Ws[cq*4+3][rr] };
        *(u16x4*)&Wt[(size_t)(n0 + rr) * DIM + k0 + cq * 4] = o;
    }
}

// ---------------------------------------------------------------------------
// bf16 MFMA GEMM: C[M,N] = A[M,K] @ Wt^T + bias.   A: bf16 [4096][1024],
// Wt: bf16 [N][K]. Tile 128x128, BK=64, 4 waves (each 64x64 = 4x4 frags of
// 16x16x32). LDS tiles stored with XOR chunk swizzle (chunk ^= row&7) so
// ds_read_b128 fragment reads are bank-conflict-free; staging uses
// global_load_lds with the inverse-swizzled global source (LDS stays linear).
// MODE 0: fused QKV — c0 selects W/bias/out, store bf16 into [B,H,T,D].
// MODE 1: single GEMM, store fp32 [M][N] (+bias).
// ---------------------------------------------------------------------------
template<int MODE>
__global__ __launch_bounds__(256)
void gemm_mfma(const u16* __restrict__ A,
               const u16* __restrict__ Wt0, const u16* __restrict__ Wt1,
               const u16* __restrict__ Wt2,
               const float* __restrict__ b0, const float* __restrict__ b1,
               const float* __restrict__ b2,
               void* __restrict__ o0, void* __restrict__ o1, void* __restrict__ o2)
{
    __shared__ __align__(16) uint8_t lds[32768];
    uint8_t* Asb = lds;            // 128 rows x 128B (64 bf16), swizzled
    uint8_t* Bsb = lds + 16384;

    const int tid  = threadIdx.x;
    const int wid  = tid >> 6, lane = tid & 63;
    const int lr   = lane & 15, lg = lane >> 4;
    const int wr   = wid >> 1, wc = wid & 1;

    const int r0 = blockIdx.x * 128;
    const int c0 = blockIdx.y * 128;

    const u16* Wt; const float* bias; u16* obf = nullptr; float* ofp = nullptr;
    int cw;
    if (MODE == 0) {
        int sel = c0 >> 10;              // 0..2 -> Q,K,V (128 | 1024)
        cw  = c0 & 1023;
        Wt   = sel == 0 ? Wt0 : sel == 1 ? Wt1 : Wt2;
        bias = sel == 0 ? b0  : sel == 1 ? b1  : b2;
        obf  = (u16*)(sel == 0 ? o0 : sel == 1 ? o1 : o2);
    } else {
        cw = c0; Wt = Wt0; bias = b0; ofp = (float*)o0;
    }

    f32x4 acc[4][4] = {};

    for (int k0 = 0; k0 < DIM; k0 += 64) {
        __syncthreads();   // previous compute done before overwrite
        #pragma unroll
        for (int seg = 0; seg < 4; ++seg) {
            int o   = seg * 4096 + tid * 16;        // linear LDS byte offset
            int row = o >> 7;                       // /128B per row
            int sch = ((o >> 4) & 7) ^ (row & 7);   // inverse-swizzled src chunk
            gload_lds16((const uint8_t*)A  + ((size_t)(r0 + row) << 11) + (k0 << 1) + (sch << 4),
                        Asb + seg * 4096 + (wid << 10) + (lane << 4));
            gload_lds16((const uint8_t*)Wt + ((size_t)(cw + row) << 11) + (k0 << 1) + (sch << 4),
                        Bsb + seg * 4096 + (wid << 10) + (lane << 4));
        }
        __syncthreads();   // staging visible (compiler drains vmcnt before barrier)

        #pragma unroll
        for (int kk = 0; kk < 2; ++kk) {
            bf16x8 a[4], b[4];
            #pragma unroll
            for (int i = 0; i < 4; ++i) {
                int ar = wr * 64 + i * 16 + lr;
                a[i] = *(const bf16x8*)(Asb + ar * 128 + ((((kk << 2) | lg) ^ (ar & 7)) << 4));
                int br = wc * 64 + i * 16 + lr;
                b[i] = *(const bf16x8*)(Bsb + br * 128 + ((((kk << 2) | lg) ^ (br & 7)) << 4));
            }
            #pragma unroll
            for (int i = 0; i < 4; ++i)
                #pragma unroll
                for (int j = 0; j < 4; ++j)
                    acc[i][j] = __builtin_amdgcn_mfma_f32_16x16x32_bf16(a[i], b[j], acc[i][j], 0, 0, 0);
        }
    }

    // Epilogue. C/D layout (m89-verified): col = lane&15, row = (lane>>4)*4+reg.
    #pragma unroll
    for (int j = 0; j < 4; ++j) {
        int colw = wc * 64 + j * 16 + lr;          // 0..127 within tile
        float bv = bias[cw + colw];
        #pragma unroll
        for (int i = 0; i < 4; ++i) {
            #pragma unroll
            for (int r = 0; r < 4; ++r) {
                float val = acc[i][j][r] + bv;
                int row = r0 + wr * 64 + i * 16 + lg * 4 + r;
                if (MODE == 0) {
                    int col = cw + colw;           // 0..1023 within this W
                    int h = col >> 6, d = col & 63;
                    int bb = row >> 11, t = row & (SEQ - 1);
                    obf[((((size_t)bb * NH + h) * SEQ + t) << 6) + d] = f2bf(val);
                } else {
                    ofp[((size_t)row << 10) + c0 + colw] = val;
                }
            }
        }
    }
}

// ---------------------------------------------------------------------------
// Flash-style causal attention, bf16 MFMA, fp32 online softmax.
// Grid (32 q-tiles, 32 b*h). 4 waves; wave w owns q-rows w*16..+15 (all d).
// Q/K staged via global_load_lds (swizzled); V transposed at stage time; P
// round-trips through swizzled LDS (same-wave write->read, in-order DS pipe).
// ---------------------------------------------------------------------------
__global__ __launch_bounds__(256)
void attn_mfma(const u16* __restrict__ q, const u16* __restrict__ k,
               const u16* __restrict__ v, u16* __restrict__ ctx)
{
    __shared__ __align__(16) uint8_t lds[32768];
    uint8_t* Qs = lds;              // [64 rows][128B] swizzled
    uint8_t* Ks = lds + 8192;
    uint8_t* Vt = lds + 16384;      // [d][kv] swizzled
    uint8_t* Ps = lds + 24576;      // [qrow][kv] swizzled

    const int tid = threadIdx.x;
    const int wid = tid >> 6, lane = tid & 63;
    const int lr  = lane & 15, lg = lane >> 4;
    const int qt  = blockIdx.x, bh = blockIdx.y;
    const size_t hb = (size_t)bh * SEQ * HD;
    const int q0 = qt * 64;

    // Stage Q tile once (2 x 4KB segments)
    #pragma unroll
    for (int seg = 0; seg < 2; ++seg) {
        int o = seg * 4096 + tid * 16;
        int row = o >> 7;
        int sch = ((o >> 4) & 7) ^ (row & 7);
        gload_lds16((const uint8_t*)(q + hb) + (size_t)(q0 + row) * 128 + (sch << 4),
                    Qs + seg * 4096 + (wid << 10) + (lane << 4));
    }

    const int vr = tid >> 2;          // kv row staged by this thread
    const int vc = (tid & 3) << 4;    // d base (16 elems)

    f32x4 acc[4] = {};
    float mrow[4] = {NEG_INF, NEG_INF, NEG_INF, NEG_INF};
    float lrow[4] = {0.f, 0.f, 0.f, 0.f};
    bf16x8 aQ0, aQ1;

    for (int kt = 0; kt <= qt; ++kt) {
        __syncthreads();   // prev iter done reading Ks/Vt (also orders Q loads)
        #pragma unroll
        for (int seg = 0; seg < 2; ++seg) {
            int o = seg * 4096 + tid * 16;
            int row = o >> 7;
            int sch = ((o >> 4) & 7) ^ (row & 7);
            gload_lds16((const uint8_t*)(k + hb) + (size_t)(kt * 64 + row) * 128 + (sch << 4),
                        Ks + seg * 4096 + (wid << 10) + (lane << 4));
        }
        {   // V transpose-stage: Vt[d][kv], swizzled; 16 scalar u16 writes
            const u16* vsrc = v + hb + ((size_t)(kt * 64 + vr) << 6) + vc;
            bf16x8 v0 = *(const bf16x8*)vsrc;
            bf16x8 v1 = *(const bf16x8*)(vsrc + 8);
            #pragma unroll
            for (int i = 0; i < 8; ++i) {
                int d0 = vc + i, d1 = vc + 8 + i;
                *(u16*)(Vt + d0 * 128 + (((vr >> 3) ^ (d0 & 7)) << 4) + ((vr & 7) << 1)) = (u16)v0[i];
                *(u16*)(Vt + d1 * 128 + (((vr >> 3) ^ (d1 & 7)) << 4) + ((vr & 7) << 1)) = (u16)v1[i];
            }
        }
        __syncthreads();

        if (kt == 0) {   // hoist Q fragments (row = w*16 + lr)
            int qr = wid * 16 + lr;
            aQ0 = *(const bf16x8*)(Qs + qr * 128 + ((lg       ^ (qr & 7)) << 4));
            aQ1 = *(const bf16x8*)(Qs + qr * 128 + (((4 | lg) ^ (qr & 7)) << 4));
        }

        // S = Q K^T : 4 kv-blocks x 2 k-halves
        f32x4 s[4];
        #pragma unroll
        for (int j = 0; j < 4; ++j) {
            int krow = j * 16 + lr;
            bf16x8 b0 = *(const bf16x8*)(Ks + krow * 128 + ((lg       ^ (krow & 7)) << 4));
            bf16x8 b1 = *(const bf16x8*)(Ks + krow * 128 + (((4 | lg) ^ (krow & 7)) << 4));
            f32x4 z = {0.f, 0.f, 0.f, 0.f};
            z    = __builtin_amdgcn_mfma_f32_16x16x32_bf16(aQ0, b0, z, 0, 0, 0);
            s[j] = __builtin_amdgcn_mfma_f32_16x16x32_bf16(aQ1, b1, z, 0, 0, 0);
        }

        #pragma unroll
        for (int j = 0; j < 4; ++j)
            #pragma unroll
            for (int r = 0; r < 4; ++r)
                s[j][r] *= 0.125f;                  // 1/sqrt(64)
        if (kt == qt) {                             // diagonal tile: causal mask
            #pragma unroll
            for (int j = 0; j < 4; ++j) {
                int kcol = j * 16 + lr;
                #pragma unroll
                for (int r = 0; r < 4; ++r)
                    if (kcol > wid * 16 + lg * 4 + r) s[j][r] = NEG_INF;
            }
        }

        // online softmax: rows = lg*4+r within wave; cols across 16-lane group
        float alpha[4];
        #pragma unroll
        for (int r = 0; r < 4; ++r) {
            float rm = fmaxf(fmaxf(s[0][r], s[1][r]), fmaxf(s[2][r], s[3][r]));
            rm = fmaxf(rm, __shfl_xor(rm, 1));
            rm = fmaxf(rm, __shfl_xor(rm, 2));
            rm = fmaxf(rm, __shfl_xor(rm, 4));
            rm = fmaxf(rm, __shfl_xor(rm, 8));
            float mn = fmaxf(mrow[r], rm);
            alpha[r] = __expf(mrow[r] - mn);        // first tile: exp(-inf)=0
            mrow[r] = mn;
        }
        float rs[4] = {0.f, 0.f, 0.f, 0.f};
        #pragma unroll
        for (int j = 0; j < 4; ++j)
            #pragma unroll
            for (int r = 0; r < 4; ++r) {
                float p = __expf(s[j][r] - mrow[r]);
                s[j][r] = p;
                rs[r] += p;
            }
        #pragma unroll
        for (int r = 0; r < 4; ++r) {
            float t = rs[r];
            t += __shfl_xor(t, 1);
            t += __shfl_xor(t, 2);
            t += __shfl_xor(t, 4);
            t += __shfl_xor(t, 8);
            lrow[r] = lrow[r] * alpha[r] + t;
        }

        // publish P (bf16, swizzled) — wave-private rows, no barrier needed
        #pragma unroll
        for (int j = 0; j < 4; ++j)
            #pragma unroll
            for (int r = 0; r < 4; ++r) {
                int row = wid * 16 + lg * 4 + r;
                int col = j * 16 + lr;
                *(u16*)(Ps + row * 128 + ((((col >> 3) ^ (row & 7)) << 4)) + ((col & 7) << 1))
                    = f2bf(s[j][r]);
            }

        #pragma unroll
        for (int ni = 0; ni < 4; ++ni)
            #pragma unroll
            for (int r = 0; r < 4; ++r)
                acc[ni][r] *= alpha[r];

        // O += P @ V
        int prow = wid * 16 + lr;
        bf16x8 pa0 = *(const bf16x8*)(Ps + prow * 128 + ((lg       ^ (prow & 7)) << 4));
        bf16x8 pa1 = *(const bf16x8*)(Ps + prow * 128 + (((4 | lg) ^ (prow & 7)) << 4));
        #pragma unroll
        for (int ni = 0; ni < 4; ++ni) {
            int vrow = ni * 16 + lr;
            bf16x8 vb0 = *(const bf16x8*)(Vt + vrow * 128 + ((lg       ^ (vrow & 7)) << 4));
            bf16x8 vb1 = *(const bf16x8*)(Vt + vrow * 128 + (((4 | lg) ^ (vrow & 7)) << 4));
            acc[ni] = __builtin_amdgcn_mfma_f32_16x16x32_bf16(pa0, vb0, acc[ni], 0, 0, 0);
            acc[ni] = __builtin_amdgcn_mfma_f32_16x16x32_bf16(pa1, vb1, acc[ni], 0, 0, 0);
        }
    }

    // ctx store: bf16 [B][T][C], C = h*64 + d
    const int b = bh >> 4, h = bh & 15;
    #pragma unroll
    for (int r = 0; r < 4; ++r) {
        float rl = 1.f / lrow[r];
        int t = q0 + wid * 16 + lg * 4 + r;
        size_t base = (((size_t)b * SEQ + t) << 10) + (h << 6);
        #pragma unroll
        for (int ni = 0; ni < 4; ++ni)
            ctx[base + ni * 16 + lr] = f2bf(acc[ni][r] * rl);
    }
}

// ---------------------------------------------------------------------------
extern "C" void kernel_launch(void* const* d_in, const int* in_sizes, int n_in,
                              void* d_out, int out_size, void* d_ws, size_t ws_size,
                              hipStream_t stream)
{
    (void)in_sizes; (void)n_in; (void)out_size; (void)ws_size;
    const float* x  = (const float*)d_in[0];
    const float* Wq = (const float*)d_in[1];
    const float* bq = (const float*)d_in[2];
    const float* Wk = (const float*)d_in[3];
    const float* bk = (const float*)d_in[4];
    const float* Wv = (const float*)d_in[5];
    const float* bv = (const float*)d_in[6];
    const float* Wo = (const float*)d_in[7];
    const float* bo = (const float*)d_in[8];

    u16* ws = (u16*)d_ws;
    const size_t M1 = (size_t)1024 * 1024;     // 1M elems
    const size_t M4 = (size_t)NROWS * DIM;     // 4M elems
    u16* xb  = ws;                 // x as bf16                     (8 MB)
    u16* wqt = ws + M4;            // W^T bf16 [n][k]               (2 MB each)
    u16* wkt = wqt + M1;
    u16* wvt = wkt + M1;
    u16* wot = wvt + M1;
    u16* qb  = wot + M1;           // q/k/v bf16 [B,H,T,D]          (8 MB each)
    u16* kb  = qb + M4;
    u16* vb  = kb + M4;
    u16* cb  = vb + M4;            // ctx bf16 [B,T,C]              (8 MB)
    // total workspace use: 48 MB

    cvt_x<<<dim3(4096), dim3(256), 0, stream>>>(x, xb);
    cvt_w<<<dim3(16, 16, 4), dim3(256), 0, stream>>>(Wq, Wk, Wv, Wo, wqt, wkt, wvt, wot);
    gemm_mfma<0><<<dim3(32, 24), dim3(256), 0, stream>>>(
        xb, wqt, wkt, wvt, bq, bk, bv, qb, kb, vb);
    attn_mfma<<<dim3(32, 32), dim3(256), 0, stream>>>(qb, kb, vb, cb);
    gemm_mfma<1><<<dim3(32, 8), dim3(256), 0, stream>>>(
        cb, wot, nullptr, nullptr, bo, nullptr, nullptr, d_out, nullptr, nullptr);
}

// Round 3
// 211.485 us; speedup vs baseline: 1.3298x; 1.3298x over previous
//
#include <hip/hip_runtime.h>
#include <hip/hip_bf16.h>
#include <stdint.h>

#define DIM    1024
#define SEQ    2048
#define NB     2
#define NH     16
#define HD     64
#define NROWS  (NB*SEQ)   // 4096

typedef unsigned short u16;
typedef __attribute__((ext_vector_type(8))) short bf16x8;
typedef __attribute__((ext_vector_type(4))) float f32x4;
typedef __attribute__((ext_vector_type(4))) unsigned short u16x4;

#define NEG_INF (-__builtin_inff())

// float -> bf16 with round-to-nearest-even
__device__ __forceinline__ u16 f2bf(float f) {
    union { float f; uint32_t u; } x; x.f = f;
    uint32_t r = x.u + 0x7FFFu + ((x.u >> 16) & 1u);
    return (u16)(r >> 16);
}

// async global->LDS, 16B per lane. LDS dest is wave-uniform base + lane*16.
__device__ __forceinline__ void gload_lds16(const void* g, void* l) {
    __builtin_amdgcn_global_load_lds(
        (const __attribute__((address_space(1))) void*)g,
        (__attribute__((address_space(3))) void*)l, 16, 0, 0);
}

// ---------------------------------------------------------------------------
// x (fp32 [4096][1024]) -> bf16. 4 elems/thread, exact cover.
// ---------------------------------------------------------------------------
__global__ __launch_bounds__(256)
void cvt_x(const float* __restrict__ in, u16* __restrict__ out)
{
    size_t i = (size_t)blockIdx.x * 256 + threadIdx.x;   // < 1048576
    float4 f = *(const float4*)&in[i * 4];
    u16x4 o = { f2bf(f.x), f2bf(f.y), f2bf(f.z), f2bf(f.w) };
    *(u16x4*)&out[i * 4] = o;
}

// ---------------------------------------------------------------------------
// W (fp32 [K=1024][N=1024]) -> Wt (bf16 [N][K]) — LDS-tiled 64x64 transpose.
// ---------------------------------------------------------------------------
__global__ __launch_bounds__(256)
void cvt_w(const float* __restrict__ Wq, const float* __restrict__ Wk,
           const float* __restrict__ Wv, const float* __restrict__ Wo,
           u16* __restrict__ Wqt, u16* __restrict__ Wkt,
           u16* __restrict__ Wvt, u16* __restrict__ Wot)
{
    __shared__ u16 Ws[64][68];
    const int z = blockIdx.z;
    const float* W = z == 0 ? Wq : z == 1 ? Wk : z == 2 ? Wv : Wo;
    u16* Wt        = z == 0 ? Wqt : z == 1 ? Wkt : z == 2 ? Wvt : Wot;
    const int k0 = blockIdx.x * 64;
    const int n0 = blockIdx.y * 64;
    const int tid = threadIdx.x;

    #pragma unroll
    for (int it = 0; it < 4; ++it) {
        int idx = tid + it * 256;
        int r = idx >> 4, cq = idx & 15;
        float4 f = *(const float4*)&W[(size_t)(k0 + r) * DIM + n0 + cq * 4];
        u16x4 o = { f2bf(f.x), f2bf(f.y), f2bf(f.z), f2bf(f.w) };
        *(u16x4*)&Ws[r][cq * 4] = o;
    }
    __syncthreads();
    #pragma unroll
    for (int it = 0; it < 4; ++it) {
        int idx = tid + it * 256;
        int rr = idx >> 4, cq = idx & 15;
        u16x4 o = { Ws[cq*4+0][rr], Ws[cq*4+1][rr], Ws[cq*4+2][rr], Ws[cq*4+3][rr] };
        *(u16x4*)&Wt[(size_t)(n0 + rr) * DIM + k0 + cq * 4] = o;
    }
}

// ---------------------------------------------------------------------------
// bf16 MFMA GEMM: C[M,N] = A[M,K] @ Wt^T + bias.  (unchanged from round 2)
// ---------------------------------------------------------------------------
template<int MODE>
__global__ __launch_bounds__(256)
void gemm_mfma(const u16* __restrict__ A,
               const u16* __restrict__ Wt0, const u16* __restrict__ Wt1,
               const u16* __restrict__ Wt2,
               const float* __restrict__ b0, const float* __restrict__ b1,
               const float* __restrict__ b2,
               void* __restrict__ o0, void* __restrict__ o1, void* __restrict__ o2)
{
    __shared__ __align__(16) uint8_t lds[32768];
    uint8_t* Asb = lds;            // 128 rows x 128B (64 bf16), swizzled
    uint8_t* Bsb = lds + 16384;

    const int tid  = threadIdx.x;
    const int wid  = tid >> 6, lane = tid & 63;
    const int lr   = lane & 15, lg = lane >> 4;
    const int wr   = wid >> 1, wc = wid & 1;

    const int r0 = blockIdx.x * 128;
    const int c0 = blockIdx.y * 128;

    const u16* Wt; const float* bias; u16* obf = nullptr; float* ofp = nullptr;
    int cw;
    if (MODE == 0) {
        int sel = c0 >> 10;              // 0..2 -> Q,K,V (128 | 1024)
        cw  = c0 & 1023;
        Wt   = sel == 0 ? Wt0 : sel == 1 ? Wt1 : Wt2;
        bias = sel == 0 ? b0  : sel == 1 ? b1  : b2;
        obf  = (u16*)(sel == 0 ? o0 : sel == 1 ? o1 : o2);
    } else {
        cw = c0; Wt = Wt0; bias = b0; ofp = (float*)o0;
    }

    f32x4 acc[4][4] = {};

    for (int k0 = 0; k0 < DIM; k0 += 64) {
        __syncthreads();   // previous compute done before overwrite
        #pragma unroll
        for (int seg = 0; seg < 4; ++seg) {
            int o   = seg * 4096 + tid * 16;        // linear LDS byte offset
            int row = o >> 7;                       // /128B per row
            int sch = ((o >> 4) & 7) ^ (row & 7);   // inverse-swizzled src chunk
            gload_lds16((const uint8_t*)A  + ((size_t)(r0 + row) << 11) + (k0 << 1) + (sch << 4),
                        Asb + seg * 4096 + (wid << 10) + (lane << 4));
            gload_lds16((const uint8_t*)Wt + ((size_t)(cw + row) << 11) + (k0 << 1) + (sch << 4),
                        Bsb + seg * 4096 + (wid << 10) + (lane << 4));
        }
        __syncthreads();   // staging visible

        __builtin_amdgcn_s_setprio(1);
        #pragma unroll
        for (int kk = 0; kk < 2; ++kk) {
            bf16x8 a[4], b[4];
            #pragma unroll
            for (int i = 0; i < 4; ++i) {
                int ar = wr * 64 + i * 16 + lr;
                a[i] = *(const bf16x8*)(Asb + ar * 128 + ((((kk << 2) | lg) ^ (ar & 7)) << 4));
                int br = wc * 64 + i * 16 + lr;
                b[i] = *(const bf16x8*)(Bsb + br * 128 + ((((kk << 2) | lg) ^ (br & 7)) << 4));
            }
            #pragma unroll
            for (int i = 0; i < 4; ++i)
                #pragma unroll
                for (int j = 0; j < 4; ++j)
                    acc[i][j] = __builtin_amdgcn_mfma_f32_16x16x32_bf16(a[i], b[j], acc[i][j], 0, 0, 0);
        }
        __builtin_amdgcn_s_setprio(0);
    }

    // Epilogue. C/D layout: col = lane&15, row = (lane>>4)*4+reg.
    #pragma unroll
    for (int j = 0; j < 4; ++j) {
        int colw = wc * 64 + j * 16 + lr;          // 0..127 within tile
        float bv = bias[cw + colw];
        #pragma unroll
        for (int i = 0; i < 4; ++i) {
            #pragma unroll
            for (int r = 0; r < 4; ++r) {
                float val = acc[i][j][r] + bv;
                int row = r0 + wr * 64 + i * 16 + lg * 4 + r;
                if (MODE == 0) {
                    int col = cw + colw;           // 0..1023 within this W
                    int h = col >> 6, d = col & 63;
                    int bb = row >> 11, t = row & (SEQ - 1);
                    obf[((((size_t)bb * NH + h) * SEQ + t) << 6) + d] = f2bf(val);
                } else {
                    ofp[((size_t)row << 10) + c0 + colw] = val;
                }
            }
        }
    }
}

// ---------------------------------------------------------------------------
// Flash-style causal attention, bf16 MFMA, fp32 online softmax.
// Grid: 1024 blocks, 1-D. Balanced remap: co-resident blocks {n, n+256,
// n+512, n+768} get qt = {ch, 15-ch, 16+ch, 31-ch} -> each CU does exactly
// 66 kv-tile iterations; all 4 blocks share one bh (K/V cache locality).
// V staged as u32 kv-pairs with (d^(d>>3)) chunk swizzle (conflict-free);
// P published with (row^(row>>2)) chunk swizzle (no cross-group aliasing).
// ---------------------------------------------------------------------------
__global__ __launch_bounds__(256)
void attn_mfma(const u16* __restrict__ q, const u16* __restrict__ k,
               const u16* __restrict__ v, u16* __restrict__ ctx)
{
    __shared__ __align__(16) uint8_t lds[32768];
    uint8_t* Qs = lds;              // [64 rows][128B] swizzled (row&7)
    uint8_t* Ks = lds + 8192;
    uint8_t* Vt = lds + 16384;      // [d][kv] swizzled (d^(d>>3))
    uint8_t* Ps = lds + 24576;      // [qrow][kv] swizzled (row^(row>>2))

    const int tid = threadIdx.x;
    const int wid = tid >> 6, lane = tid & 63;
    const int lr  = lane & 15, lg = lane >> 4;

    const int n  = blockIdx.x;
    const int j4 = n >> 8;
    const int c  = n & 255;
    const int ch = c >> 5;
    const int bh = c & 31;
    const int qt = (j4 == 0) ? ch : (j4 == 1) ? (15 - ch)
                 : (j4 == 2) ? (16 + ch) : (31 - ch);

    const size_t hb = (size_t)bh * SEQ * HD;
    const int q0 = qt * 64;

    // Stage Q tile once (2 x 4KB segments)
    #pragma unroll
    for (int seg = 0; seg < 2; ++seg) {
        int o = seg * 4096 + tid * 16;
        int row = o >> 7;
        int sch = ((o >> 4) & 7) ^ (row & 7);
        gload_lds16((const uint8_t*)(q + hb) + (size_t)(q0 + row) * 128 + (sch << 4),
                    Qs + seg * 4096 + (wid << 10) + (lane << 4));
    }

    const int vp = tid >> 3;          // kv pair index 0..31 (rows 2vp, 2vp+1)
    const int vg = tid & 7;           // d-group (8 d-elems each)

    f32x4 acc[4] = {};
    float mrow[4] = {NEG_INF, NEG_INF, NEG_INF, NEG_INF};
    float lrow[4] = {0.f, 0.f, 0.f, 0.f};
    bf16x8 aQ0, aQ1;

    for (int kt = 0; kt <= qt; ++kt) {
        __syncthreads();   // prev iter done reading Ks/Vt (also orders Q loads)
        #pragma unroll
        for (int seg = 0; seg < 2; ++seg) {
            int o = seg * 4096 + tid * 16;
            int row = o >> 7;
            int sch = ((o >> 4) & 7) ^ (row & 7);
            gload_lds16((const uint8_t*)(k + hb) + (size_t)(kt * 64 + row) * 128 + (sch << 4),
                        Ks + seg * 4096 + (wid << 10) + (lane << 4));
        }
        {   // V stage: Vt[d][kv] as u32 kv-pairs, conflict-free swizzle
            const u16* vsrc = v + hb + ((size_t)(kt * 64 + 2 * vp) << 6) + vg * 8;
            bf16x8 v0 = *(const bf16x8*)vsrc;          // row 2vp
            bf16x8 v1 = *(const bf16x8*)(vsrc + 64);   // row 2vp+1
            #pragma unroll
            for (int i = 0; i < 8; ++i) {
                int d = vg * 8 + i;
                int swzd = (d ^ (d >> 3)) & 7;
                uint32_t w = (uint32_t)(u16)v0[i] | ((uint32_t)(u16)v1[i] << 16);
                *(uint32_t*)(Vt + d * 128 + ((((vp >> 2) ^ swzd) << 4)) + ((vp & 3) << 2)) = w;
            }
        }
        __syncthreads();

        if (kt == 0) {   // hoist Q fragments (row = w*16 + lr)
            int qr = wid * 16 + lr;
            aQ0 = *(const bf16x8*)(Qs + qr * 128 + ((lg       ^ (qr & 7)) << 4));
            aQ1 = *(const bf16x8*)(Qs + qr * 128 + (((4 | lg) ^ (qr & 7)) << 4));
        }

        // S = Q K^T : 4 kv-blocks x 2 k-halves
        f32x4 s[4];
        __builtin_amdgcn_s_setprio(1);
        #pragma unroll
        for (int j = 0; j < 4; ++j) {
            int krow = j * 16 + lr;
            bf16x8 b0 = *(const bf16x8*)(Ks + krow * 128 + ((lg       ^ (krow & 7)) << 4));
            bf16x8 b1 = *(const bf16x8*)(Ks + krow * 128 + (((4 | lg) ^ (krow & 7)) << 4));
            f32x4 z = {0.f, 0.f, 0.f, 0.f};
            z    = __builtin_amdgcn_mfma_f32_16x16x32_bf16(aQ0, b0, z, 0, 0, 0);
            s[j] = __builtin_amdgcn_mfma_f32_16x16x32_bf16(aQ1, b1, z, 0, 0, 0);
        }
        __builtin_amdgcn_s_setprio(0);

        #pragma unroll
        for (int j = 0; j < 4; ++j)
            #pragma unroll
            for (int r = 0; r < 4; ++r)
                s[j][r] *= 0.125f;                  // 1/sqrt(64)
        if (kt == qt) {                             // diagonal tile: causal mask
            #pragma unroll
            for (int j = 0; j < 4; ++j) {
                int kcol = j * 16 + lr;
                #pragma unroll
                for (int r = 0; r < 4; ++r)
                    if (kcol > wid * 16 + lg * 4 + r) s[j][r] = NEG_INF;
            }
        }

        // online softmax: rows = lg*4+r within wave; cols across 16-lane group
        float alpha[4];
        #pragma unroll
        for (int r = 0; r < 4; ++r) {
            float rm = fmaxf(fmaxf(s[0][r], s[1][r]), fmaxf(s[2][r], s[3][r]));
            rm = fmaxf(rm, __shfl_xor(rm, 1));
            rm = fmaxf(rm, __shfl_xor(rm, 2));
            rm = fmaxf(rm, __shfl_xor(rm, 4));
            rm = fmaxf(rm, __shfl_xor(rm, 8));
            float mn = fmaxf(mrow[r], rm);
            alpha[r] = __expf(mrow[r] - mn);        // first tile: exp(-inf)=0
            mrow[r] = mn;
        }
        float rs[4] = {0.f, 0.f, 0.f, 0.f};
        #pragma unroll
        for (int j = 0; j < 4; ++j)
            #pragma unroll
            for (int r = 0; r < 4; ++r) {
                float p = __expf(s[j][r] - mrow[r]);
                s[j][r] = p;
                rs[r] += p;
            }
        #pragma unroll
        for (int r = 0; r < 4; ++r) {
            float t = rs[r];
            t += __shfl_xor(t, 1);
            t += __shfl_xor(t, 2);
            t += __shfl_xor(t, 4);
            t += __shfl_xor(t, 8);
            lrow[r] = lrow[r] * alpha[r] + t;
        }

        // publish P (bf16, swizzled) — wave-private rows, no barrier needed
        #pragma unroll
        for (int j = 0; j < 4; ++j)
            #pragma unroll
            for (int r = 0; r < 4; ++r) {
                int row = wid * 16 + lg * 4 + r;
                int swzp = (row ^ (row >> 2)) & 7;
                int col = j * 16 + lr;
                *(u16*)(Ps + row * 128 + ((((col >> 3) ^ swzp) << 4)) + ((col & 7) << 1))
                    = f2bf(s[j][r]);
            }

        #pragma unroll
        for (int ni = 0; ni < 4; ++ni)
            #pragma unroll
            for (int r = 0; r < 4; ++r)
                acc[ni][r] *= alpha[r];

        // O += P @ V
        int prow = wid * 16 + lr;
        int swzq = (prow ^ (prow >> 2)) & 7;
        bf16x8 pa0 = *(const bf16x8*)(Ps + prow * 128 + ((lg       ^ swzq) << 4));
        bf16x8 pa1 = *(const bf16x8*)(Ps + prow * 128 + (((4 | lg) ^ swzq) << 4));
        __builtin_amdgcn_s_setprio(1);
        #pragma unroll
        for (int ni = 0; ni < 4; ++ni) {
            int vrow = ni * 16 + lr;
            int swzd = (vrow ^ (vrow >> 3)) & 7;
            bf16x8 vb0 = *(const bf16x8*)(Vt + vrow * 128 + ((lg       ^ swzd) << 4));
            bf16x8 vb1 = *(const bf16x8*)(Vt + vrow * 128 + (((4 | lg) ^ swzd) << 4));
            acc[ni] = __builtin_amdgcn_mfma_f32_16x16x32_bf16(pa0, vb0, acc[ni], 0, 0, 0);
            acc[ni] = __builtin_amdgcn_mfma_f32_16x16x32_bf16(pa1, vb1, acc[ni], 0, 0, 0);
        }
        __builtin_amdgcn_s_setprio(0);
    }

    // ctx store: bf16 [B][T][C], C = h*64 + d
    const int b = bh >> 4, h = bh & 15;
    #pragma unroll
    for (int r = 0; r < 4; ++r) {
        float rl = 1.f / lrow[r];
        int t = q0 + wid * 16 + lg * 4 + r;
        size_t base = (((size_t)b * SEQ + t) << 10) + (h << 6);
        #pragma unroll
        for (int ni = 0; ni < 4; ++ni)
            ctx[base + ni * 16 + lr] = f2bf(acc[ni][r] * rl);
    }
}

// ---------------------------------------------------------------------------
extern "C" void kernel_launch(void* const* d_in, const int* in_sizes, int n_in,
                              void* d_out, int out_size, void* d_ws, size_t ws_size,
                              hipStream_t stream)
{
    (void)in_sizes; (void)n_in; (void)out_size; (void)ws_size;
    const float* x  = (const float*)d_in[0];
    const float* Wq = (const float*)d_in[1];
    const float* bq = (const float*)d_in[2];
    const float* Wk = (const float*)d_in[3];
    const float* bk = (const float*)d_in[4];
    const float* Wv = (const float*)d_in[5];
    const float* bv = (const float*)d_in[6];
    const float* Wo = (const float*)d_in[7];
    const float* bo = (const float*)d_in[8];

    u16* ws = (u16*)d_ws;
    const size_t M1 = (size_t)1024 * 1024;     // 1M elems
    const size_t M4 = (size_t)NROWS * DIM;     // 4M elems
    u16* xb  = ws;                 // x as bf16                     (8 MB)
    u16* wqt = ws + M4;            // W^T bf16 [n][k]               (2 MB each)
    u16* wkt = wqt + M1;
    u16* wvt = wkt + M1;
    u16* wot = wvt + M1;
    u16* qb  = wot + M1;           // q/k/v bf16 [B,H,T,D]          (8 MB each)
    u16* kb  = qb + M4;
    u16* vb  = kb + M4;
    u16* cb  = vb + M4;            // ctx bf16 [B,T,C]              (8 MB)
    // total workspace use: 48 MB

    cvt_x<<<dim3(4096), dim3(256), 0, stream>>>(x, xb);
    cvt_w<<<dim3(16, 16, 4), dim3(256), 0, stream>>>(Wq, Wk, Wv, Wo, wqt, wkt, wvt, wot);
    gemm_mfma<0><<<dim3(32, 24), dim3(256), 0, stream>>>(
        xb, wqt, wkt, wvt, bq, bk, bv, qb, kb, vb);
    attn_mfma<<<dim3(1024), dim3(256), 0, stream>>>(qb, kb, vb, cb);
    gemm_mfma<1><<<dim3(32, 8), dim3(256), 0, stream>>>(
        cb, wot, nullptr, nullptr, bo, nullptr, nullptr, d_out, nullptr, nullptr);
}

// Round 4
// 190.784 us; speedup vs baseline: 1.4741x; 1.1085x over previous
//
#include <hip/hip_runtime.h>
#include <hip/hip_bf16.h>
#include <stdint.h>

#define DIM    1024
#define SEQ    2048
#define NB     2
#define NH     16
#define HD     64
#define NROWS  (NB*SEQ)   // 4096

typedef unsigned short u16;
typedef __attribute__((ext_vector_type(8))) short bf16x8;
typedef __attribute__((ext_vector_type(4))) float f32x4;
typedef __attribute__((ext_vector_type(4))) unsigned short u16x4;

#define NEG_INF (-__builtin_inff())

// float -> bf16 with round-to-nearest-even
__device__ __forceinline__ u16 f2bf(float f) {
    union { float f; uint32_t u; } x; x.f = f;
    uint32_t r = x.u + 0x7FFFu + ((x.u >> 16) & 1u);
    return (u16)(r >> 16);
}

// async global->LDS, 16B per lane. LDS dest is wave-uniform base + lane*16.
__device__ __forceinline__ void gload_lds16(const void* g, void* l) {
    __builtin_amdgcn_global_load_lds(
        (const __attribute__((address_space(1))) void*)g,
        (__attribute__((address_space(3))) void*)l, 16, 0, 0);
}

// ---------------------------------------------------------------------------
// x (fp32 [4096][1024]) -> bf16. 4 elems/thread, exact cover.
// ---------------------------------------------------------------------------
__global__ __launch_bounds__(256)
void cvt_x(const float* __restrict__ in, u16* __restrict__ out)
{
    size_t i = (size_t)blockIdx.x * 256 + threadIdx.x;   // < 1048576
    float4 f = *(const float4*)&in[i * 4];
    u16x4 o = { f2bf(f.x), f2bf(f.y), f2bf(f.z), f2bf(f.w) };
    *(u16x4*)&out[i * 4] = o;
}

// ---------------------------------------------------------------------------
// W (fp32 [K=1024][N=1024]) -> Wt (bf16 [N][K]) — LDS-tiled 64x64 transpose.
// ---------------------------------------------------------------------------
__global__ __launch_bounds__(256)
void cvt_w(const float* __restrict__ Wq, const float* __restrict__ Wk,
           const float* __restrict__ Wv, const float* __restrict__ Wo,
           u16* __restrict__ Wqt, u16* __restrict__ Wkt,
           u16* __restrict__ Wvt, u16* __restrict__ Wot)
{
    __shared__ u16 Ws[64][68];
    const int z = blockIdx.z;
    const float* W = z == 0 ? Wq : z == 1 ? Wk : z == 2 ? Wv : Wo;
    u16* Wt        = z == 0 ? Wqt : z == 1 ? Wkt : z == 2 ? Wvt : Wot;
    const int k0 = blockIdx.x * 64;
    const int n0 = blockIdx.y * 64;
    const int tid = threadIdx.x;

    #pragma unroll
    for (int it = 0; it < 4; ++it) {
        int idx = tid + it * 256;
        int r = idx >> 4, cq = idx & 15;
        float4 f = *(const float4*)&W[(size_t)(k0 + r) * DIM + n0 + cq * 4];
        u16x4 o = { f2bf(f.x), f2bf(f.y), f2bf(f.z), f2bf(f.w) };
        *(u16x4*)&Ws[r][cq * 4] = o;
    }
    __syncthreads();
    #pragma unroll
    for (int it = 0; it < 4; ++it) {
        int idx = tid + it * 256;
        int rr = idx >> 4, cq = idx & 15;
        u16x4 o = { Ws[cq*4+0][rr], Ws[cq*4+1][rr], Ws[cq*4+2][rr], Ws[cq*4+3][rr] };
        *(u16x4*)&Wt[(size_t)(n0 + rr) * DIM + k0 + cq * 4] = o;
    }
}

// ---------------------------------------------------------------------------
// bf16 MFMA GEMM: C[M,N] = A[M,K] @ Wt^T + bias.
// MODE 0: fused QKV; Q output (sel==0) pre-scaled by 1/sqrt(HD)=0.125
// (exact power-of-2 scaling in bf16) so attention skips the scale.
// MODE 1: single GEMM, fp32 out.
// ---------------------------------------------------------------------------
template<int MODE>
__global__ __launch_bounds__(256)
void gemm_mfma(const u16* __restrict__ A,
               const u16* __restrict__ Wt0, const u16* __restrict__ Wt1,
               const u16* __restrict__ Wt2,
               const float* __restrict__ b0, const float* __restrict__ b1,
               const float* __restrict__ b2,
               void* __restrict__ o0, void* __restrict__ o1, void* __restrict__ o2)
{
    __shared__ __align__(16) uint8_t lds[32768];
    uint8_t* Asb = lds;            // 128 rows x 128B (64 bf16), swizzled
    uint8_t* Bsb = lds + 16384;

    const int tid  = threadIdx.x;
    const int wid  = tid >> 6, lane = tid & 63;
    const int lr   = lane & 15, lg = lane >> 4;
    const int wr   = wid >> 1, wc = wid & 1;

    const int r0 = blockIdx.x * 128;
    const int c0 = blockIdx.y * 128;

    const u16* Wt; const float* bias; u16* obf = nullptr; float* ofp = nullptr;
    int cw; float qscale = 1.0f;
    if (MODE == 0) {
        int sel = c0 >> 10;              // 0..2 -> Q,K,V (128 | 1024)
        cw  = c0 & 1023;
        Wt   = sel == 0 ? Wt0 : sel == 1 ? Wt1 : Wt2;
        bias = sel == 0 ? b0  : sel == 1 ? b1  : b2;
        obf  = (u16*)(sel == 0 ? o0 : sel == 1 ? o1 : o2);
        if (sel == 0) qscale = 0.125f;
    } else {
        cw = c0; Wt = Wt0; bias = b0; ofp = (float*)o0;
    }

    f32x4 acc[4][4] = {};

    for (int k0 = 0; k0 < DIM; k0 += 64) {
        __syncthreads();   // previous compute done before overwrite
        #pragma unroll
        for (int seg = 0; seg < 4; ++seg) {
            int o   = seg * 4096 + tid * 16;        // linear LDS byte offset
            int row = o >> 7;                       // /128B per row
            int sch = ((o >> 4) & 7) ^ (row & 7);   // inverse-swizzled src chunk
            gload_lds16((const uint8_t*)A  + ((size_t)(r0 + row) << 11) + (k0 << 1) + (sch << 4),
                        Asb + seg * 4096 + (wid << 10) + (lane << 4));
            gload_lds16((const uint8_t*)Wt + ((size_t)(cw + row) << 11) + (k0 << 1) + (sch << 4),
                        Bsb + seg * 4096 + (wid << 10) + (lane << 4));
        }
        __syncthreads();   // staging visible

        __builtin_amdgcn_s_setprio(1);
        #pragma unroll
        for (int kk = 0; kk < 2; ++kk) {
            bf16x8 a[4], b[4];
            #pragma unroll
            for (int i = 0; i < 4; ++i) {
                int ar = wr * 64 + i * 16 + lr;
                a[i] = *(const bf16x8*)(Asb + ar * 128 + ((((kk << 2) | lg) ^ (ar & 7)) << 4));
                int br = wc * 64 + i * 16 + lr;
                b[i] = *(const bf16x8*)(Bsb + br * 128 + ((((kk << 2) | lg) ^ (br & 7)) << 4));
            }
            #pragma unroll
            for (int i = 0; i < 4; ++i)
                #pragma unroll
                for (int j = 0; j < 4; ++j)
                    acc[i][j] = __builtin_amdgcn_mfma_f32_16x16x32_bf16(a[i], b[j], acc[i][j], 0, 0, 0);
        }
        __builtin_amdgcn_s_setprio(0);
    }

    // Epilogue. C/D layout: col = lane&15, row = (lane>>4)*4+reg.
    #pragma unroll
    for (int j = 0; j < 4; ++j) {
        int colw = wc * 64 + j * 16 + lr;          // 0..127 within tile
        float bv = bias[cw + colw];
        #pragma unroll
        for (int i = 0; i < 4; ++i) {
            #pragma unroll
            for (int r = 0; r < 4; ++r) {
                float val = (acc[i][j][r] + bv) * qscale;
                int row = r0 + wr * 64 + i * 16 + lg * 4 + r;
                if (MODE == 0) {
                    int col = cw + colw;           // 0..1023 within this W
                    int h = col >> 6, d = col & 63;
                    int bb = row >> 11, t = row & (SEQ - 1);
                    obf[((((size_t)bb * NH + h) * SEQ + t) << 6) + d] = f2bf(val);
                } else {
                    ofp[((size_t)row << 10) + c0 + colw] = val;
                }
            }
        }
    }
}

// ---------------------------------------------------------------------------
// Flash-style causal attention, bf16 MFMA, swapped-QK^T in-register softmax.
//
// S^T = mfma(A=K_frag, B=Q_frag): lane holds S[q = q0+wid*16+(lane&15)]
// [kv = kt*64 + j*16 + (lane>>4)*4 + r] — one q-row per lane, 16 kv/iter.
// Softmax: in-lane tree + 2 shfl_xor (lanes ^16,^32 share the q-row).
// PV k-permutation kv -> (st=j&1, k=lg*8+(j>>1)*4+r) makes the P A-fragment
// purely in-lane (no shuffles, no LDS); V staged into permuted slots so the
// B-fragment reads stay single b128. O rescale via 4 __shfl of alpha.
// Q pre-scaled by 0.125 in the QKV GEMM. Balanced causal remap as R3.
// ---------------------------------------------------------------------------
__global__ __launch_bounds__(256)
void attn_mfma(const u16* __restrict__ q, const u16* __restrict__ k,
               const u16* __restrict__ v, u16* __restrict__ ctx)
{
    __shared__ __align__(16) uint8_t lds[24576];
    uint8_t* Qs = lds;              // [64 rows][128B] swizzled (row&7)
    uint8_t* Ks = lds + 8192;
    uint8_t* Vt = lds + 16384;      // [d][slot] swizzled (d^(d>>3))

    const int tid = threadIdx.x;
    const int wid = tid >> 6, lane = tid & 63;
    const int lr  = lane & 15, lg = lane >> 4;

    const int n  = blockIdx.x;
    const int j4 = n >> 8;
    const int c  = n & 255;
    const int ch = c >> 5;
    const int bh = c & 31;
    const int qt = (j4 == 0) ? ch : (j4 == 1) ? (15 - ch)
                 : (j4 == 2) ? (16 + ch) : (31 - ch);

    const size_t hb = (size_t)bh * SEQ * HD;
    const int q0 = qt * 64;

    // Stage Q tile once (2 x 4KB segments)
    #pragma unroll
    for (int seg = 0; seg < 2; ++seg) {
        int o = seg * 4096 + tid * 16;
        int row = o >> 7;
        int sch = ((o >> 4) & 7) ^ (row & 7);
        gload_lds16((const uint8_t*)(q + hb) + (size_t)(q0 + row) * 128 + (sch << 4),
                    Qs + seg * 4096 + (wid << 10) + (lane << 4));
    }

    const int vp = tid >> 3;          // kv pair (rows 2vp, 2vp+1)
    const int vg = tid & 7;           // d-group (8 d-elems)
    // slot(kv): j=kv>>4, lgh=(kv>>2)&3, r=kv&3 -> s=(j&1)*32+lgh*8+(j>>1)*4+r
    const int vj  = vp >> 3;               // (2vp)>>4
    const int vlg = (vp >> 1) & 3;         // ((2vp)>>2)&3
    const int vrr = (vp & 1) * 2;          // (2vp)&3
    const int vslot = (vj & 1) * 32 + vlg * 8 + ((vj >> 1) << 2) + vrr;  // even

    f32x4 acc[4] = {};
    float m_own = NEG_INF;   // running max for q-row q0 + wid*16 + lr
    float l_own = 0.f;
    bf16x8 aQ0, aQ1;

    for (int kt = 0; kt <= qt; ++kt) {
        __syncthreads();   // prev iter done reading Ks/Vt (also orders Q loads)
        #pragma unroll
        for (int seg = 0; seg < 2; ++seg) {
            int o = seg * 4096 + tid * 16;
            int row = o >> 7;
            int sch = ((o >> 4) & 7) ^ (row & 7);
            gload_lds16((const uint8_t*)(k + hb) + (size_t)(kt * 64 + row) * 128 + (sch << 4),
                        Ks + seg * 4096 + (wid << 10) + (lane << 4));
        }
        {   // V stage into permuted slots, u32 kv-pairs, swizzled chunks
            const u16* vsrc = v + hb + ((size_t)(kt * 64 + 2 * vp) << 6) + vg * 8;
            bf16x8 v0 = *(const bf16x8*)vsrc;          // row 2vp
            bf16x8 v1 = *(const bf16x8*)(vsrc + 64);   // row 2vp+1
            #pragma unroll
            for (int i = 0; i < 8; ++i) {
                int d = vg * 8 + i;
                int swzd = (d ^ (d >> 3)) & 7;
                uint32_t w = (uint32_t)(u16)v0[i] | ((uint32_t)(u16)v1[i] << 16);
                *(uint32_t*)(Vt + d * 128 + ((((vslot >> 3) ^ swzd) << 4))
                             + ((vslot & 7) << 1)) = w;
            }
        }
        __syncthreads();

        if (kt == 0) {   // hoist Q fragments (row = wid*16 + lr)
            int qr = wid * 16 + lr;
            aQ0 = *(const bf16x8*)(Qs + qr * 128 + ((lg       ^ (qr & 7)) << 4));
            aQ1 = *(const bf16x8*)(Qs + qr * 128 + (((4 | lg) ^ (qr & 7)) << 4));
        }

        // S^T = K·Q : A = K fragment, B = Q fragment (swapped operands)
        f32x4 s[4];
        __builtin_amdgcn_s_setprio(1);
        #pragma unroll
        for (int j = 0; j < 4; ++j) {
            int krow = j * 16 + lr;
            bf16x8 b0 = *(const bf16x8*)(Ks + krow * 128 + ((lg       ^ (krow & 7)) << 4));
            bf16x8 b1 = *(const bf16x8*)(Ks + krow * 128 + (((4 | lg) ^ (krow & 7)) << 4));
            f32x4 z = {0.f, 0.f, 0.f, 0.f};
            z    = __builtin_amdgcn_mfma_f32_16x16x32_bf16(b0, aQ0, z, 0, 0, 0);
            s[j] = __builtin_amdgcn_mfma_f32_16x16x32_bf16(b1, aQ1, z, 0, 0, 0);
        }
        __builtin_amdgcn_s_setprio(0);

        if (kt == qt) {                  // causal mask (tile-relative)
            #pragma unroll
            for (int j = 0; j < 4; ++j)
                #pragma unroll
                for (int r = 0; r < 4; ++r)
                    if (j * 16 + lg * 4 + r > wid * 16 + lr) s[j][r] = NEG_INF;
        }

        // in-register softmax over this lane's 16 kv values
        float rm = NEG_INF;
        #pragma unroll
        for (int j = 0; j < 4; ++j) {
            float a = fmaxf(fmaxf(s[j][0], s[j][1]), fmaxf(s[j][2], s[j][3]));
            rm = fmaxf(rm, a);
        }
        rm = fmaxf(rm, __shfl_xor(rm, 16));
        rm = fmaxf(rm, __shfl_xor(rm, 32));
        float mnew = fmaxf(m_own, rm);
        float aown = __expf(m_own - mnew);   // first tile: exp(-inf)=0
        m_own = mnew;

        float rs = 0.f;
        #pragma unroll
        for (int j = 0; j < 4; ++j)
            #pragma unroll
            for (int r = 0; r < 4; ++r) {
                float p = __expf(s[j][r] - mnew);
                s[j][r] = p;
                rs += p;
            }
        rs += __shfl_xor(rs, 16);
        rs += __shfl_xor(rs, 32);
        l_own = l_own * aown + rs;

        // alpha for O rows (q_local = lg*4+r) held by lane (lg*4+r)
        float ar[4];
        #pragma unroll
        for (int r = 0; r < 4; ++r) ar[r] = __shfl(aown, lg * 4 + r);
        #pragma unroll
        for (int ni = 0; ni < 4; ++ni)
            #pragma unroll
            for (int r = 0; r < 4; ++r)
                acc[ni][r] *= ar[r];

        // P A-fragments, purely in-lane: frag[st][i] = s[st+2*(i>>2)][i&3]
        bf16x8 pa0, pa1;
        #pragma unroll
        for (int i = 0; i < 4; ++i) {
            pa0[i]     = (short)f2bf(s[0][i]);
            pa0[4 + i] = (short)f2bf(s[2][i]);
            pa1[i]     = (short)f2bf(s[1][i]);
            pa1[4 + i] = (short)f2bf(s[3][i]);
        }

        // O += P @ V   (B = V from permuted slots; chunks st*4+lg)
        __builtin_amdgcn_s_setprio(1);
        #pragma unroll
        for (int ni = 0; ni < 4; ++ni) {
            int vrow = ni * 16 + lr;
            int swzd = (vrow ^ (vrow >> 3)) & 7;
            bf16x8 vb0 = *(const bf16x8*)(Vt + vrow * 128 + ((lg       ^ swzd) << 4));
            bf16x8 vb1 = *(const bf16x8*)(Vt + vrow * 128 + (((4 | lg) ^ swzd) << 4));
            acc[ni] = __builtin_amdgcn_mfma_f32_16x16x32_bf16(pa0, vb0, acc[ni], 0, 0, 0);
            acc[ni] = __builtin_amdgcn_mfma_f32_16x16x32_bf16(pa1, vb1, acc[ni], 0, 0, 0);
        }
        __builtin_amdgcn_s_setprio(0);
    }

    // epilogue: O rows q_local = lg*4+r, cols d = ni*16+lr; 1/l via shfl
    float rinv = 1.f / l_own;
    float rl[4];
    #pragma unroll
    for (int r = 0; r < 4; ++r) rl[r] = __shfl(rinv, lg * 4 + r);

    const int b = bh >> 4, h = bh & 15;
    #pragma unroll
    for (int r = 0; r < 4; ++r) {
        int t = q0 + wid * 16 + lg * 4 + r;
        size_t base = (((size_t)b * SEQ + t) << 10) + (h << 6);
        #pragma unroll
        for (int ni = 0; ni < 4; ++ni)
            ctx[base + ni * 16 + lr] = f2bf(acc[ni][r] * rl[r]);
    }
}

// ---------------------------------------------------------------------------
extern "C" void kernel_launch(void* const* d_in, const int* in_sizes, int n_in,
                              void* d_out, int out_size, void* d_ws, size_t ws_size,
                              hipStream_t stream)
{
    (void)in_sizes; (void)n_in; (void)out_size; (void)ws_size;
    const float* x  = (const float*)d_in[0];
    const float* Wq = (const float*)d_in[1];
    const float* bq = (const float*)d_in[2];
    const float* Wk = (const float*)d_in[3];
    const float* bk = (const float*)d_in[4];
    const float* Wv = (const float*)d_in[5];
    const float* bv = (const float*)d_in[6];
    const float* Wo = (const float*)d_in[7];
    const float* bo = (const float*)d_in[8];

    u16* ws = (u16*)d_ws;
    const size_t M1 = (size_t)1024 * 1024;     // 1M elems
    const size_t M4 = (size_t)NROWS * DIM;     // 4M elems
    u16* xb  = ws;                 // x as bf16                     (8 MB)
    u16* wqt = ws + M4;            // W^T bf16 [n][k]               (2 MB each)
    u16* wkt = wqt + M1;
    u16* wvt = wkt + M1;
    u16* wot = wvt + M1;
    u16* qb  = wot + M1;           // q/k/v bf16 [B,H,T,D]          (8 MB each)
    u16* kb  = qb + M4;
    u16* vb  = kb + M4;
    u16* cb  = vb + M4;            // ctx bf16 [B,T,C]              (8 MB)
    // total workspace use: 48 MB

    cvt_x<<<dim3(4096), dim3(256), 0, stream>>>(x, xb);
    cvt_w<<<dim3(16, 16, 4), dim3(256), 0, stream>>>(Wq, Wk, Wv, Wo, wqt, wkt, wvt, wot);
    gemm_mfma<0><<<dim3(32, 24), dim3(256), 0, stream>>>(
        xb, wqt, wkt, wvt, bq, bk, bv, qb, kb, vb);
    attn_mfma<<<dim3(1024), dim3(256), 0, stream>>>(qb, kb, vb, cb);
    gemm_mfma<1><<<dim3(32, 8), dim3(256), 0, stream>>>(
        cb, wot, nullptr, nullptr, bo, nullptr, nullptr, d_out, nullptr, nullptr);
}